// Round 4
// baseline (226.143 us; speedup 1.0000x reference)
//
#include <hip/hip_runtime.h>
#include <cmath>

#define BINS 10
#define EDGE_TOP (1.0f + 1e-6f)
#define BLK 256

// Classify via native v_exp_f32 (fast). Near-bin-boundary values are
// recomputed with double-precision exp so the fp32 result matches numpy's
// fp32 exp. Error analysis: __expf rel. error <= ~4e-7 (1 ulp v_exp + arg
// rounding), so in g*10 space (g<=1, ef<=2) the fast/numpy disagreement band
// is <= 8e-6; margin 4e-5 is 5x safe. Hazard rate ~8e-5/elem -> the branch
// is taken for ~0.5% of wave-groups (execz-skipped otherwise).
// Machinery proven in R1-R3: absmax 7.8e-3 vs threshold 0.385, zero misbins.
__device__ __forceinline__ void ghm_classify_fast(float p, int& bin, bool& lt_top) {
    float ef  = __expf(-p);
    float g   = fabsf(ef - 1.0f);
    float g10 = g * 10.0f;
    int   b   = (int)g10;          // g >= 0, trunc == floor (saturating cvt)
    float fb  = (float)b;
    bool hazard = (g10 - fb < 4e-5f) || (fb + 1.0f - g10 < 4e-5f) ||
                  (fabsf(g - EDGE_TOP) < 4e-6f);
    if (hazard) {
        double ed = exp(-(double)p);
        float ef2 = (float)ed;     // ~correctly-rounded fp32 exp
        g   = fabsf(ef2 - 1.0f);
        g10 = g * 10.0f;
        b   = (int)g10;
    }
    bin    = (b < 9) ? b : 9;
    lt_top = (g < EDGE_TOP);
}

// Pass 1: per-bin counts + total valid count + 4-bit code per element
// (bin, or 15 if not in-bin; 4 codes per u16, one u16 per float4 group).
// Histogram: ONE u64 per thread, 10 x 6-bit fields (<=60 elems/thread
// enforced by launcher -> no overflow). Loop: explicit 1-ahead register
// prefetch so next iteration's 2 float4 loads are in flight during the
// current iteration's compute (R3's 16-deep unroll defeated pipelining;
// warm==cold at 76us proved it was issue-bound, not BW-bound).
__global__ __launch_bounds__(BLK) void ghm_hist(
    const float* __restrict__ pred, const float* __restrict__ lw,
    unsigned int* __restrict__ cnt, unsigned short* __restrict__ codes, int n)
{
    unsigned long long h = 0ull;
    unsigned int vcnt = 0;   // wave-total via ballot/popcount (scalar pipe)

    const int tid = blockIdx.x * BLK + threadIdx.x;
    const int S   = gridDim.x * BLK;
    const int n4  = n >> 2;
    const float4* p4 = (const float4*)pred;
    const float4* w4 = (const float4*)lw;

    int i = tid;
    if (i < n4) {
        float4 P0 = p4[i];
        float4 W0 = w4[i];
        while (true) {
            const int inext = i + S;
            const bool more = inext < n4;
            float4 P1, W1;
            if (more) { P1 = p4[inext]; W1 = w4[inext]; }  // prefetch next

            float ps[4] = {P0.x, P0.y, P0.z, P0.w};
            float ws[4] = {W0.x, W0.y, W0.z, W0.w};
            unsigned int code = 0u;
#pragma unroll
            for (int k = 0; k < 4; ++k) {
                bool valid = ws[k] > 0.0f;
                vcnt += (unsigned int)__popcll(__ballot(valid));
                int bin; bool lt;
                ghm_classify_fast(ps[k], bin, lt);
                bool ib = valid && lt;
                h += ib ? (1ull << (unsigned)(bin * 6)) : 0ull;
                unsigned int idx = ib ? (unsigned int)bin : 15u;
                code |= idx << (k * 4);
            }
            codes[i] = (unsigned short)code;

            if (!more) break;
            i = inext; P0 = P1; W0 = W1;
        }
    }
    // scalar tail (n % 4): counts only; apply recomputes these directly
    if (tid == 0) {
        for (int j = n4 << 2; j < n; ++j) {
            bool valid = lw[j] > 0.0f;
            int bin; bool lt;
            ghm_classify_fast(pred[j], bin, lt);
            // tail runs with one active lane; ballot==1 iff valid
            vcnt += (valid && true) ? 1u : 0u;
            h += (valid && lt) ? (1ull << (unsigned)(bin * 6)) : 0ull;
        }
    }

    // combine: bins via wave shuffle-reduce -> LDS -> 11 global atomics/block;
    // vcnt is wave-uniform (ballot-summed), lane 0 reports. Lanes exit the
    // grid-stride loop low-lane-last, so lane 0 always holds the full sum.
    __shared__ unsigned int sc[BINS + 1];
    if (threadIdx.x < BINS + 1) sc[threadIdx.x] = 0u;
    __syncthreads();
#pragma unroll
    for (int b = 0; b < BINS; ++b) {
        unsigned int v = (unsigned int)((h >> (6 * b)) & 63ull);
#pragma unroll
        for (int off = 32; off > 0; off >>= 1)
            v += __shfl_down(v, off, 64);
        if ((threadIdx.x & 63) == 0) atomicAdd(&sc[b], v);
    }
    if ((threadIdx.x & 63) == 0) atomicAdd(&sc[BINS], vcnt);
    __syncthreads();
    if (threadIdx.x < BINS + 1) atomicAdd(&cnt[threadIdx.x], sc[threadIdx.x]);
}

// Wave-cooperative finalize (proven R2/R3): lane b<10 holds w[b]; lane 15
// holds 0.0 -> sentinel code 15 yields weight 0 via ds_bpermute.
// fp32 op order matches reference: (tot/counts[b]) / n_nonempty.
__device__ __forceinline__ int ghm_wave_weights(const unsigned int* __restrict__ cnt) {
    const int lane = threadIdx.x & 63;
    unsigned int cv = cnt[lane < 10 ? lane : 10];
    float totf = fmaxf((float)__shfl((int)cv, 10, 64), 1.0f);
    unsigned long long nem = __ballot(lane < 10 && cv > 0u);
    int nne = __popcll(nem);
    float nf = fmaxf((float)nne, 1.0f);
    float wfl = 0.0f;
    if (lane < 10 && cv > 0u) {
        wfl = totf / (float)cv;
        if (nne > 0) wfl = wfl / nf;
    }
    return __float_as_int(wfl);
}

// Pass 2: out = w[code] * pred. Reads pred + codes only (no lw, no exp).
// ~5 VALU/elem (bfe, lshl, bpermute, mul, pack) + prefetched loads.
__global__ __launch_bounds__(BLK) void ghm_apply(
    const float* __restrict__ pred, const float* __restrict__ lw,
    const unsigned short* __restrict__ codes,
    const unsigned int* __restrict__ cnt, float* __restrict__ out, int n)
{
    const int wfi = ghm_wave_weights(cnt);

    const int tid = blockIdx.x * BLK + threadIdx.x;
    const int S   = gridDim.x * BLK;
    const int n4  = n >> 2;
    const float4* p4 = (const float4*)pred;
    float4* o4       = (float4*)out;

    int i = tid;
    if (i < n4) {
        float4 P0 = p4[i];
        unsigned int c0 = codes[i];
        while (true) {
            const int inext = i + S;
            const bool more = inext < n4;
            float4 P1; unsigned int c1 = 0u;
            if (more) { P1 = p4[inext]; c1 = codes[inext]; }  // prefetch next

            float ps[4] = {P0.x, P0.y, P0.z, P0.w};
            float os[4];
#pragma unroll
            for (int k = 0; k < 4; ++k) {
                unsigned int idx = (c0 >> (k * 4)) & 15u;
                float wt = __int_as_float(
                    __builtin_amdgcn_ds_bpermute((int)(idx << 2), wfi));
                os[k] = wt * ps[k];
            }
            float4 O;
            O.x = os[0]; O.y = os[1]; O.z = os[2]; O.w = os[3];
            o4[i] = O;

            if (!more) break;
            i = inext; P0 = P1; c0 = c1;
        }
    }
    // scalar tail: recompute directly (codes not written for these)
    if (tid == 0) {
        for (int j = n4 << 2; j < n; ++j) {
            int bin; bool lt;
            ghm_classify_fast(pred[j], bin, lt);
            bool ib = (lw[j] > 0.0f) && lt;
            unsigned int idx = ib ? (unsigned int)bin : 15u;
            float wt = __int_as_float(
                __builtin_amdgcn_ds_bpermute((int)(idx << 2), wfi));
            out[j] = wt * pred[j];
        }
    }
}

extern "C" void kernel_launch(void* const* d_in, const int* in_sizes, int n_in,
                              void* d_out, int out_size, void* d_ws, size_t ws_size,
                              hipStream_t stream)
{
    const float* pred = (const float*)d_in[0];
    // d_in[1] = target, unused by the math
    const float* lw   = (const float*)d_in[2];
    float* out        = (float*)d_out;
    const int n       = in_sizes[0];
    const int n4      = n >> 2;

    unsigned int* cnt     = (unsigned int*)d_ws;   // [0..9]=bins, [10]=valid
    unsigned short* codes = (unsigned short*)((char*)d_ws + 64);

    // ws is poisoned 0xAA before every call — zero the counters on-stream.
    hipMemsetAsync(d_ws, 0, (BINS + 1) * sizeof(unsigned int), stream);

    // G=2000: n4=4.096M -> exactly 8 float4s (32 elems) per thread.
    // Keep <=15 float4s (60 elems) per thread so 6-bit packed histogram
    // fields can't overflow (max 60 + 3 tail = 63).
    int G = 2000;
    while ((long long)(n4 + (long long)G * BLK - 1) / ((long long)G * BLK) > 15)
        G *= 2;

    ghm_hist <<<G, BLK, 0, stream>>>(pred, lw, cnt, codes, n);
    ghm_apply<<<G, BLK, 0, stream>>>(pred, lw, codes, cnt, out, n);
}